// Round 5
// baseline (1102.186 us; speedup 1.0000x reference)
//
#include <hip/hip_runtime.h>
#include <cstdint>

// Problem constants
#define E_ 8
#define D_ 1024
#define H_ 4096
#define NTOK 16384   // B*S = 4*4096

typedef unsigned short ushort_t;
typedef __attribute__((ext_vector_type(8))) short short8;
typedef __attribute__((ext_vector_type(4))) float f32x4;

__device__ __forceinline__ ushort_t f2bf(float f) {
  uint32_t u = __builtin_bit_cast(uint32_t, f);
  uint32_t r = (u + 0x7fffu + ((u >> 16) & 1u)) >> 16;  // RNE
  return (ushort_t)r;
}

__device__ __forceinline__ void gload_lds16(const void* g, void* l) {
  __builtin_amdgcn_global_load_lds(
      (const __attribute__((address_space(1))) uint32_t*)g,
      (__attribute__((address_space(3))) uint32_t*)l, 16, 0, 0);
}

// ---------------- init: zero counts/cursor + rawbase ----------------
__global__ void init_kernel(int* counts_cursor, float* rawbase) {
  int tid = threadIdx.x + blockIdx.x * 256;
  if (tid < 16) counts_cursor[tid] = 0;
  if (tid < E_ * D_) rawbase[tid] = 0.f;   // grid 32*256 = 8192 threads
}

// ---------------- transpose fp32 [E][R][C] -> bf16 [E][C][R], 64x64 tiles ----------------
// bf16 stored transposed in LDS during load; ushort4 (8B) coalesced global writes.
// FUSE=1 (W2 path): also accumulate rawbase[e][d] += sum_h relu(b1[e][h]) * W2[e][h][d]
// (saves a separate full read of W2).
template <int FUSE>
__global__ void transpose_bf16(const float* __restrict__ in, ushort_t* __restrict__ out,
                               int R, int C, const float* __restrict__ b1,
                               float* __restrict__ rawbase) {
  __shared__ ushort_t t[64][66];   // [c][r], pad 2 -> conflict-free u16 writes
  __shared__ float relu_b1[64];
  __shared__ float colsum[4][64];
  const int e = blockIdx.z;
  const float* ip = in + (size_t)e * R * C;
  ushort_t* op = out + (size_t)e * R * C;
  const int c0 = blockIdx.x * 64, r0 = blockIdx.y * 64;
  const int tid = threadIdx.x;
  const int w = tid >> 6, cl = tid & 63;
  if (FUSE) {
    if (tid < 64) relu_b1[tid] = fmaxf(b1[e * R + r0 + tid], 0.f);
    __syncthreads();
  }
  float s = 0.f;
#pragma unroll
  for (int q = 0; q < 16; ++q) {
    int r = q * 4 + w;
    float v = ip[(size_t)(r0 + r) * C + c0 + cl];
    t[cl][r] = f2bf(v);
    if (FUSE) s += relu_b1[r] * v;
  }
  if (FUSE) colsum[w][cl] = s;
  __syncthreads();
  if (FUSE && tid < 64) {
    float tot = colsum[0][tid] + colsum[1][tid] + colsum[2][tid] + colsum[3][tid];
    atomicAdd(&rawbase[e * D_ + c0 + tid], tot);
  }
#pragma unroll
  for (int it = 0; it < 4; ++it) {
    int c = it * 16 + (tid >> 4);
    int rg = (tid & 15) * 4;
    ushort4 v;
    v.x = t[c][rg + 0];
    v.y = t[c][rg + 1];
    v.z = t[c][rg + 2];
    v.w = t[c][rg + 3];
    *(ushort4*)&op[(size_t)(c0 + c) * R + r0 + rg] = v;
  }
}

// adj[e][d] = sum_i (rawbase[i][d] + b2[i][d]) - rawbase[e][d]
__global__ void adj_kernel(const float* __restrict__ rawbase, const float* __restrict__ b2,
                           float* __restrict__ adj) {
  int i = blockIdx.x * 256 + threadIdx.x;  // 8192
  int d = i & (D_ - 1);
  int e = i >> 10;
  float tot = 0.f;
#pragma unroll
  for (int ii = 0; ii < E_; ++ii) tot += rawbase[ii * D_ + d] + b2[ii * D_ + d];
  adj[i] = tot - rawbase[e * D_ + d];
}

// ---------------- router: fp32 logits -> argmax (first-max tiebreak), count per expert ----------------
__global__ void router_kernel(const float* __restrict__ x, const float* __restrict__ Wr,
                              const float* __restrict__ br, int* __restrict__ idx,
                              int* __restrict__ counts) {
  __shared__ float wr_s[E_][D_];   // transposed Wr: wr_s[e][d]
  const int tid = threadIdx.x;
  for (int j = tid; j < E_ * D_; j += 256) {
    int e = j & 7, d = j >> 3;
    wr_s[e][d] = Wr[j];
  }
  __syncthreads();
  const int wid = tid >> 6, l = tid & 63;
  const int t0 = blockIdx.x * 32 + wid * 8;
  for (int tt = 0; tt < 8; ++tt) {
    int t = t0 + tt;
    const float* xr = x + (size_t)t * D_;
    float s[E_];
#pragma unroll
    for (int e = 0; e < E_; ++e) s[e] = 0.f;
    for (int q = 0; q < D_ / 64; ++q) {
      float xv = xr[q * 64 + l];
#pragma unroll
      for (int e = 0; e < E_; ++e) s[e] += xv * wr_s[e][q * 64 + l];
    }
#pragma unroll
    for (int e = 0; e < E_; ++e) {
#pragma unroll
      for (int off = 32; off > 0; off >>= 1) s[e] += __shfl_xor(s[e], off, 64);
    }
    if (l == 0) {
      float best = s[0] + br[0];
      int bi = 0;
#pragma unroll
      for (int e = 1; e < E_; ++e) {
        float v = s[e] + br[e];
        if (v > best) { best = v; bi = e; }   // strict >: first-max like argmax
      }
      idx[t] = bi;
      atomicAdd(&counts[bi], 1);
    }
  }
}

// ---------------- scan + build compact tile worklists (128x128 tiles) ----------------
// item = (e<<16) | (tm<<8) | tn.  meta: [0]=n1 [1]=n2
__global__ void scan_build(const int* __restrict__ counts, int* __restrict__ offsets,
                           int* __restrict__ work1, int* __restrict__ work2,
                           int* __restrict__ meta) {
  if (threadIdx.x != 0 || blockIdx.x != 0) return;
  int acc = 0;
  int cnt[E_];
  for (int e = 0; e < E_; ++e) {
    cnt[e] = counts[e];
    offsets[e] = acc;
    acc += cnt[e];
  }
  offsets[E_] = acc;
  int n1 = 0, n2 = 0;
  for (int e = 0; e < E_; ++e) {
    int nt = (cnt[e] + 127) >> 7;
    for (int tn = 0; tn < H_ / 128; ++tn)
      for (int tm = 0; tm < nt; ++tm)
        work1[n1++] = (e << 16) | (tm << 8) | tn;
    for (int tn = 0; tn < D_ / 128; ++tn)
      for (int tm = 0; tm < nt; ++tm)
        work2[n2++] = (e << 16) | (tm << 8) | tn;
  }
  meta[0] = n1;
  meta[1] = n2;
}

// ---------------- scatter: counting-sort tokens, gather x -> bf16 xg ----------------
__global__ void scatter_kernel(const float* __restrict__ x, const int* __restrict__ idx,
                               const int* __restrict__ offsets, int* __restrict__ cursor,
                               int* __restrict__ perm, ushort_t* __restrict__ xg) {
  const int tid = threadIdx.x;
  const int wid = tid >> 6, l = tid & 63;
  const int t = blockIdx.x * 4 + wid;
  int e = idx[t];
  int slot = 0;
  if (l == 0) {
    slot = offsets[e] + atomicAdd(&cursor[e], 1);
    perm[slot] = t;
  }
  slot = __shfl(slot, 0, 64);
  const float4* xr = (const float4*)(x + (size_t)t * D_);
  ushort_t* xo = xg + (size_t)slot * D_;
#pragma unroll
  for (int q = 0; q < 4; ++q) {
    float4 v = xr[q * 64 + l];
    ushort4 o;
    o.x = f2bf(v.x); o.y = f2bf(v.y); o.z = f2bf(v.z); o.w = f2bf(v.w);
    *(ushort4*)(xo + (size_t)(q * 64 + l) * 4) = o;
  }
}

// ---------------- grouped GEMM: m97 structure. 128x128 tile, BK=64, single-buffered ----------------
// 256 threads = 4 waves (2 M x 2 N), per-wave output 64x64. LDS: {A,B} of [128][64] bf16 = 32 KiB
// -> 4-5 blocks/CU; implicit wave-level overlap does the pipelining (m97/m103: 912 TF @128^2).
// XOR swizzle on 16B units: LDS[row][u] holds global unit u^(row&7) via pre-swizzled global
// source (linear global_load_lds dest); ds_read applies same XOR -> 0 bank conflicts.
// One tile per block (compact worklist, no dud blocks) + m204 bijective XCD swizzle.
// MODE 1: hb = relu(xg @ W1t^T + b1) (bf16) ; MODE 2: out[perm] = hb @ W2t^T + adj (f32)

template <int MODE>
__global__ __launch_bounds__(256) void ffn_gemm(
    const ushort_t* __restrict__ A_all, const ushort_t* __restrict__ Bw,
    const float* __restrict__ bias, const int* __restrict__ offs,
    const int* __restrict__ perm, float* __restrict__ out, ushort_t* __restrict__ hbo,
    const int* __restrict__ work, const int* __restrict__ nw_p) {
  constexpr int Kd = (MODE == 1) ? D_ : H_;
  constexpr int Nd = (MODE == 1) ? H_ : D_;
  constexpr int NKT = Kd / 64;

  const int n1 = *nw_p;
  int bid = blockIdx.x;
  if (bid >= n1) return;
  {  // m204 bijective XCD swizzle over the worklist
    int q = n1 >> 3, r = n1 & 7;
    int xcd = bid & 7, pos = bid >> 3;
    bid = (xcd < r ? xcd * (q + 1) : r * (q + 1) + (xcd - r) * q) + pos;
  }
  const int item = work[bid];
  const int e = item >> 16, tm = (item >> 8) & 255, tn = item & 255;
  const int ms = offs[e];
  const int M = offs[e + 1] - ms;

  __shared__ __align__(16) ushort_t lA[128 * 64];
  __shared__ __align__(16) ushort_t lB[128 * 64];

  const int tid = threadIdx.x;
  const int wid = tid >> 6, l = tid & 63;
  const int wm = wid >> 1, wn = wid & 1;
  const int lr = l & 15, lh = l >> 4, lx = l & 7;

  const ushort_t* Ab = A_all + (size_t)ms * Kd;
  const ushort_t* Bb = Bw + (size_t)e * ((size_t)Nd * Kd);
  const int arow0 = tm * 128;
  const int brow0 = tn * 128;
  const int rowmaxA = M - 1;

  // per-thread staging offsets (elements), pre-swizzled source unit
  int aoff[4], boff[4];
#pragma unroll
  for (int c = 0; c < 4; ++c) {
    int idx = c * 256 + tid;          // 0..1023 lane-slots, 16B each
    int lrow = idx >> 3;              // 0..127
    int u = (idx & 7) ^ (lrow & 7);   // pre-swizzled 16B unit
    int ga = arow0 + lrow;
    if (ga > rowmaxA) ga = rowmaxA;
    aoff[c] = ga * Kd + u * 8;
    boff[c] = (brow0 + lrow) * Kd + u * 8;
  }

#define STAGE(kt)                                                                        \
  _Pragma("unroll") for (int c_ = 0; c_ < 4; ++c_) {                                     \
    gload_lds16(Ab + aoff[c_] + (kt) * 64, &lA[(c_ * 256 + wid * 64) * 8]);              \
    gload_lds16(Bb + boff[c_] + (kt) * 64, &lB[(c_ * 256 + wid * 64) * 8]);              \
  }

  f32x4 acc[4][4];
#pragma unroll
  for (int i = 0; i < 4; ++i)
#pragma unroll
    for (int j = 0; j < 4; ++j) acc[i][j] = (f32x4){0.f, 0.f, 0.f, 0.f};

  for (int kt = 0; kt < NKT; ++kt) {
    STAGE(kt)
    __syncthreads();   // drains vmcnt: tile staged for all waves
#pragma unroll
    for (int ks = 0; ks < 2; ++ks) {
      short8 af[4], bq[4];
      const int uo = (((ks * 4 + lh) ^ lx) << 3);
#pragma unroll
      for (int i = 0; i < 4; ++i)
        af[i] = *(const short8*)&lA[(wm * 64 + i * 16 + lr) * 64 + uo];
#pragma unroll
      for (int j = 0; j < 4; ++j)
        bq[j] = *(const short8*)&lB[(wn * 64 + j * 16 + lr) * 64 + uo];
#pragma unroll
      for (int i = 0; i < 4; ++i)
#pragma unroll
        for (int j = 0; j < 4; ++j)
          acc[i][j] = __builtin_amdgcn_mfma_f32_16x16x32_bf16(af[i], bq[j], acc[i][j], 0, 0, 0);
    }
    __syncthreads();   // protect LDS before next STAGE overwrite
  }

  // epilogue: C[row = tm*128 + wm*64 + i*16 + lh*4 + rr][col = tn*128 + wn*64 + j*16 + lr]
  const int gcolbase = tn * 128 + wn * 64 + lr;
  float bv[4];
#pragma unroll
  for (int j = 0; j < 4; ++j) bv[j] = bias[e * Nd + gcolbase + j * 16];
#pragma unroll
  for (int i = 0; i < 4; ++i) {
#pragma unroll
    for (int rr = 0; rr < 4; ++rr) {
      int grow = tm * 128 + wm * 64 + i * 16 + lh * 4 + rr;
      if (grow < M) {
        if (MODE == 1) {
          size_t rowoff = (size_t)(ms + grow) * H_;
#pragma unroll
          for (int j = 0; j < 4; ++j) {
            float v = acc[i][j][rr] + bv[j];
            v = fmaxf(v, 0.f);
            hbo[rowoff + gcolbase + j * 16] = f2bf(v);
          }
        } else {
          int tok = perm[ms + grow];
          size_t rowoff = (size_t)tok * D_;
#pragma unroll
          for (int j = 0; j < 4; ++j)
            out[rowoff + gcolbase + j * 16] = acc[i][j][rr] + bv[j];
        }
      }
    }
  }
#undef STAGE
}

extern "C" void kernel_launch(void* const* d_in, const int* in_sizes, int n_in,
                              void* d_out, int out_size, void* d_ws, size_t ws_size,
                              hipStream_t stream) {
  const float* x  = (const float*)d_in[0];
  const float* W1 = (const float*)d_in[1];
  const float* b1 = (const float*)d_in[2];
  const float* W2 = (const float*)d_in[3];
  const float* b2 = (const float*)d_in[4];
  const float* Wr = (const float*)d_in[5];
  const float* br = (const float*)d_in[6];
  float* out = (float*)d_out;

  // workspace layout (needs ~302.3 MB)
  char* ws = (char*)d_ws;
  ushort_t* W1t   = (ushort_t*)(ws);                    // [E][H][D] bf16: 67108864 B
  ushort_t* W2t   = (ushort_t*)(ws + 67108864);         // [E][D][H] bf16: 67108864 B
  ushort_t* xg    = (ushort_t*)(ws + 134217728);        // [N][D]   bf16: 33554432 B
  ushort_t* hb    = (ushort_t*)(ws + 167772160);        // [N][H]   bf16: 134217728 B
  float*    rawbase = (float*)(ws + 301989888);         // [E][D] f32
  float*    adj   = (float*)(ws + 302022656);           // [E][D] f32
  int*      idx   = (int*)(ws + 302055424);             // [N]
  int*      perm  = (int*)(ws + 302120960);             // [N]
  int*      counts = (int*)(ws + 302186496);            // 8 + 8 cursor
  int*      cursor = counts + 8;
  int*      offsets = (int*)(ws + 302186624);           // 9 ints
  int*      meta   = (int*)(ws + 302186752);            // [n1, n2]
  int*      work1  = (int*)(ws + 302186880);            // <=8192 ints
  int*      work2  = (int*)(ws + 302219648);            // <=8192 ints

  init_kernel<<<32, 256, 0, stream>>>(counts, rawbase);
  transpose_bf16<0><<<dim3(H_ / 64, D_ / 64, E_), 256, 0, stream>>>(W1, W1t, D_, H_,
                                                                    nullptr, nullptr);
  transpose_bf16<1><<<dim3(D_ / 64, H_ / 64, E_), 256, 0, stream>>>(W2, W2t, H_, D_,
                                                                    b1, rawbase);
  adj_kernel<<<32, 256, 0, stream>>>(rawbase, b2, adj);
  router_kernel<<<512, 256, 0, stream>>>(x, Wr, br, idx, counts);
  scan_build<<<1, 64, 0, stream>>>(counts, offsets, work1, work2, meta);
  scatter_kernel<<<NTOK / 4, 256, 0, stream>>>(x, idx, offsets, cursor, perm, xg);
  // worst-case tile counts: sum_e ceil(cnt_e/128) <= 135  ->  135*32=4320, 135*8=1080
  ffn_gemm<1><<<4320, 256, 0, stream>>>(xg, W1t, b1, offsets, nullptr, nullptr, hb,
                                        work1, meta + 0);
  ffn_gemm<2><<<1080, 256, 0, stream>>>(hb, W2t, adj, offsets, perm, out, nullptr,
                                        work2, meta + 1);
}

// Round 6
// 908.545 us; speedup vs baseline: 1.2131x; 1.2131x over previous
//
#include <hip/hip_runtime.h>
#include <cstdint>

// Problem constants
#define E_ 8
#define D_ 1024
#define H_ 4096
#define NTOK 16384   // B*S = 4*4096

typedef unsigned short ushort_t;
typedef __attribute__((ext_vector_type(8))) short short8;
typedef __attribute__((ext_vector_type(4))) float f32x4;

__device__ __forceinline__ ushort_t f2bf(float f) {
  uint32_t u = __builtin_bit_cast(uint32_t, f);
  uint32_t r = (u + 0x7fffu + ((u >> 16) & 1u)) >> 16;  // RNE
  return (ushort_t)r;
}

__device__ __forceinline__ void gload_lds16(const void* g, void* l) {
  __builtin_amdgcn_global_load_lds(
      (const __attribute__((address_space(1))) uint32_t*)g,
      (__attribute__((address_space(3))) uint32_t*)l, 16, 0, 0);
}

// ---------------- init: zero counts/cursor + rawbase ----------------
__global__ void init_kernel(int* counts_cursor, float* rawbase) {
  int tid = threadIdx.x + blockIdx.x * 256;
  if (tid < 16) counts_cursor[tid] = 0;
  if (tid < E_ * D_) rawbase[tid] = 0.f;   // grid 32*256 = 8192 threads
}

// ---------------- transpose fp32 [E][R][C] -> bf16 [E][C][R], 64x64 tiles ----------------
// bf16 stored transposed in LDS during load; ushort4 (8B) coalesced global writes.
// FUSE=1 (W2 path): also accumulate rawbase[e][d] += sum_h relu(b1[e][h]) * W2[e][h][d]
template <int FUSE>
__global__ void transpose_bf16(const float* __restrict__ in, ushort_t* __restrict__ out,
                               int R, int C, const float* __restrict__ b1,
                               float* __restrict__ rawbase) {
  __shared__ ushort_t t[64][66];   // [c][r], pad 2 -> conflict-free u16 writes
  __shared__ float relu_b1[64];
  __shared__ float colsum[4][64];
  const int e = blockIdx.z;
  const float* ip = in + (size_t)e * R * C;
  ushort_t* op = out + (size_t)e * R * C;
  const int c0 = blockIdx.x * 64, r0 = blockIdx.y * 64;
  const int tid = threadIdx.x;
  const int w = tid >> 6, cl = tid & 63;
  if (FUSE) {
    if (tid < 64) relu_b1[tid] = fmaxf(b1[e * R + r0 + tid], 0.f);
    __syncthreads();
  }
  float s = 0.f;
#pragma unroll
  for (int q = 0; q < 16; ++q) {
    int r = q * 4 + w;
    float v = ip[(size_t)(r0 + r) * C + c0 + cl];
    t[cl][r] = f2bf(v);
    if (FUSE) s += relu_b1[r] * v;
  }
  if (FUSE) colsum[w][cl] = s;
  __syncthreads();
  if (FUSE && tid < 64) {
    float tot = colsum[0][tid] + colsum[1][tid] + colsum[2][tid] + colsum[3][tid];
    atomicAdd(&rawbase[e * D_ + c0 + tid], tot);
  }
#pragma unroll
  for (int it = 0; it < 4; ++it) {
    int c = it * 16 + (tid >> 4);
    int rg = (tid & 15) * 4;
    ushort4 v;
    v.x = t[c][rg + 0];
    v.y = t[c][rg + 1];
    v.z = t[c][rg + 2];
    v.w = t[c][rg + 3];
    *(ushort4*)&op[(size_t)(c0 + c) * R + r0 + rg] = v;
  }
}

// adj[e][d] = sum_i (rawbase[i][d] + b2[i][d]) - rawbase[e][d]
__global__ void adj_kernel(const float* __restrict__ rawbase, const float* __restrict__ b2,
                           float* __restrict__ adj) {
  int i = blockIdx.x * 256 + threadIdx.x;  // 8192
  int d = i & (D_ - 1);
  int e = i >> 10;
  float tot = 0.f;
#pragma unroll
  for (int ii = 0; ii < E_; ++ii) tot += rawbase[ii * D_ + d] + b2[ii * D_ + d];
  adj[i] = tot - rawbase[e * D_ + d];
}

// ---------------- router: fp32 logits -> argmax (first-max tiebreak), count per expert ----------------
__global__ void router_kernel(const float* __restrict__ x, const float* __restrict__ Wr,
                              const float* __restrict__ br, int* __restrict__ idx,
                              int* __restrict__ counts) {
  __shared__ float wr_s[E_][D_];   // transposed Wr: wr_s[e][d]
  const int tid = threadIdx.x;
  for (int j = tid; j < E_ * D_; j += 256) {
    int e = j & 7, d = j >> 3;
    wr_s[e][d] = Wr[j];
  }
  __syncthreads();
  const int wid = tid >> 6, l = tid & 63;
  const int t0 = blockIdx.x * 32 + wid * 8;
  for (int tt = 0; tt < 8; ++tt) {
    int t = t0 + tt;
    const float* xr = x + (size_t)t * D_;
    float s[E_];
#pragma unroll
    for (int e = 0; e < E_; ++e) s[e] = 0.f;
    for (int q = 0; q < D_ / 64; ++q) {
      float xv = xr[q * 64 + l];
#pragma unroll
      for (int e = 0; e < E_; ++e) s[e] += xv * wr_s[e][q * 64 + l];
    }
#pragma unroll
    for (int e = 0; e < E_; ++e) {
#pragma unroll
      for (int off = 32; off > 0; off >>= 1) s[e] += __shfl_xor(s[e], off, 64);
    }
    if (l == 0) {
      float best = s[0] + br[0];
      int bi = 0;
#pragma unroll
      for (int e = 1; e < E_; ++e) {
        float v = s[e] + br[e];
        if (v > best) { best = v; bi = e; }   // strict >: first-max like argmax
      }
      idx[t] = bi;
      atomicAdd(&counts[bi], 1);
    }
  }
}

// ---------------- scan + build compact tile worklists (256x256 tiles) ----------------
// item = (e<<16) | (tm<<8) | tn.  meta: [0]=n1 [1]=n2
__global__ void scan_build(const int* __restrict__ counts, int* __restrict__ offsets,
                           int* __restrict__ work1, int* __restrict__ work2,
                           int* __restrict__ meta) {
  if (threadIdx.x != 0 || blockIdx.x != 0) return;
  int acc = 0;
  int cnt[E_];
  for (int e = 0; e < E_; ++e) {
    cnt[e] = counts[e];
    offsets[e] = acc;
    acc += cnt[e];
  }
  offsets[E_] = acc;
  int n1 = 0, n2 = 0;
  for (int e = 0; e < E_; ++e) {
    int nt = (cnt[e] + 255) >> 8;
    for (int tn = 0; tn < H_ / 256; ++tn)
      for (int tm = 0; tm < nt; ++tm)
        work1[n1++] = (e << 16) | (tm << 8) | tn;
    for (int tn = 0; tn < D_ / 256; ++tn)
      for (int tm = 0; tm < nt; ++tm)
        work2[n2++] = (e << 16) | (tm << 8) | tn;
  }
  meta[0] = n1;
  meta[1] = n2;
}

// ---------------- scatter: counting-sort tokens, gather x -> bf16 xg ----------------
__global__ void scatter_kernel(const float* __restrict__ x, const int* __restrict__ idx,
                               const int* __restrict__ offsets, int* __restrict__ cursor,
                               int* __restrict__ perm, ushort_t* __restrict__ xg) {
  const int tid = threadIdx.x;
  const int wid = tid >> 6, l = tid & 63;
  const int t = blockIdx.x * 4 + wid;
  int e = idx[t];
  int slot = 0;
  if (l == 0) {
    slot = offsets[e] + atomicAdd(&cursor[e], 1);
    perm[slot] = t;
  }
  slot = __shfl(slot, 0, 64);
  const float4* xr = (const float4*)(x + (size_t)t * D_);
  ushort_t* xo = xg + (size_t)slot * D_;
#pragma unroll
  for (int q = 0; q < 4; ++q) {
    float4 v = xr[q * 64 + l];
    ushort4 o;
    o.x = f2bf(v.x); o.y = f2bf(v.y); o.z = f2bf(v.z); o.w = f2bf(v.w);
    *(ushort4*)(xo + (size_t)(q * 64 + l) * 4) = o;
  }
}

// ---------------- grouped GEMM: 256x256 tile, BK=32, 4-buffer stage-ahead-3 pipeline ----------------
// 512 threads = 8 waves (2 M x 4 N), per-wave output 128x64. LDS: 4 bufs x {A,B} of 16 KiB
// (128 KiB). Logical rows are 64B at BK=32, so two logical rows pack into one 128B physical
// row of 8 16B-units; XOR swizzle U = (u + 4*(r&1)) ^ (P&7) keeps ds_read_b128 aliasing at
// 2-way (free, m136). Staging uses pre-swizzled global source + linear global_load_lds dest.
// Schedule per K-step (T3/T4): STAGE(kt+3, clamped) -> 12 ds_read_b128 + 32 MFMA on buf[kt&3]
// -> s_waitcnt vmcnt(8) (completes kt+1's 4 loads; kt+2/kt+3 stay in flight) -> raw s_barrier.
// Loads get ~3 steps of latency coverage and issue continuously. Per-wave waits + barrier
// compose (m201 pattern). MODE 1: hb = relu(xg@W1t^T+b1) bf16 ; MODE 2: out[perm] = hb@W2t^T+adj.

template <int MODE>
__global__ __launch_bounds__(512, 2) void ffn_gemm(
    const ushort_t* __restrict__ A_all, const ushort_t* __restrict__ Bw,
    const float* __restrict__ bias, const int* __restrict__ offs,
    const int* __restrict__ perm, float* __restrict__ out, ushort_t* __restrict__ hbo,
    const int* __restrict__ work, const int* __restrict__ nw_p) {
  constexpr int Kd = (MODE == 1) ? D_ : H_;
  constexpr int Nd = (MODE == 1) ? H_ : D_;
  constexpr int NKT = Kd / 32;

  const int n1 = *nw_p;
  int bid = blockIdx.x;
  if (bid >= n1) return;
  {  // m204 bijective XCD swizzle over the worklist
    int q = n1 >> 3, r = n1 & 7;
    int xcd = bid & 7, pos = bid >> 3;
    bid = (xcd < r ? xcd * (q + 1) : r * (q + 1) + (xcd - r) * q) + pos;
  }
  const int item = work[bid];
  const int e = item >> 16, tm = (item >> 8) & 255, tn = item & 255;
  const int ms = offs[e];
  const int M = offs[e + 1] - ms;

  __shared__ __align__(16) ushort_t lds[4][2][8192];  // 4 bufs x {A,B} x 16KB = 128 KiB

  const int tid = threadIdx.x;
  const int wid = tid >> 6, l = tid & 63;
  const int wm = wid >> 2, wn = wid & 3;
  const int lr = l & 15, lh = l >> 4;

  const ushort_t* Ab = A_all + (size_t)ms * Kd;
  const ushort_t* Bb = Bw + (size_t)e * ((size_t)Nd * Kd);
  const int arow0 = tm * 256;
  const int brow0 = tn * 256;
  const int rowmaxA = M - 1;

  // per-thread staging source offsets (elements). Slot s -> phys row P=s>>3, stored unit
  // U=s&7; logical unit Ur = U ^ (P&7); logical row r = 2P + (Ur>>2), col-unit u = Ur&3.
  int a_src[2], b_src[2];
#pragma unroll
  for (int c = 0; c < 2; ++c) {
    int s = c * 512 + tid;
    int P = s >> 3, U = s & 7;
    int Ur = U ^ (P & 7);
    int r = 2 * P + (Ur >> 2);
    int u = Ur & 3;
    int ga = arow0 + r;
    if (ga > rowmaxA) ga = rowmaxA;
    a_src[c] = ga * Kd + u * 8;
    b_src[c] = (brow0 + r) * Kd + u * 8;
  }

#define STAGE(buf, kt)                                                                   \
  _Pragma("unroll") for (int c_ = 0; c_ < 2; ++c_) {                                     \
    gload_lds16(Ab + a_src[c_] + (kt) * 32, &lds[buf][0][(c_ * 512 + wid * 64) * 8]);    \
    gload_lds16(Bb + b_src[c_] + (kt) * 32, &lds[buf][1][(c_ * 512 + wid * 64) * 8]);    \
  }

// logical (r, lh) -> ushort offset within a 16KB half
#define AOFF(r) (((((r) >> 1)) << 6) + ((((lh) + (((r) & 1) << 2)) ^ (((r) >> 1) & 7)) << 3))

  f32x4 acc[8][4];
#pragma unroll
  for (int i = 0; i < 8; ++i)
#pragma unroll
    for (int j = 0; j < 4; ++j) acc[i][j] = (f32x4){0.f, 0.f, 0.f, 0.f};

  // prologue: 3 K-tiles in flight
  STAGE(0, 0)
  STAGE(1, 1)
  STAGE(2, 2)
  asm volatile("s_waitcnt vmcnt(8)" ::: "memory");   // buf0's 4 loads complete
  __builtin_amdgcn_s_barrier();

#pragma unroll 4
  for (int kt = 0; kt < NKT; ++kt) {
    int pf = kt + 3;
    if (pf > NKT - 1) pf = NKT - 1;   // clamped prefetch: uniform vmcnt accounting
    STAGE((kt + 3) & 3, pf)
    const ushort_t* la = &lds[kt & 3][0][0];
    const ushort_t* lb = &lds[kt & 3][1][0];
    short8 af[8], bq[4];
#pragma unroll
    for (int i = 0; i < 8; ++i)
      af[i] = *(const short8*)&la[AOFF(wm * 128 + i * 16 + lr)];
#pragma unroll
    for (int j = 0; j < 4; ++j)
      bq[j] = *(const short8*)&lb[AOFF(wn * 64 + j * 16 + lr)];
#pragma unroll
    for (int i = 0; i < 8; ++i)
#pragma unroll
      for (int j = 0; j < 4; ++j)
        acc[i][j] = __builtin_amdgcn_mfma_f32_16x16x32_bf16(af[i], bq[j], acc[i][j], 0, 0, 0);
    asm volatile("s_waitcnt vmcnt(8)" ::: "memory");  // kt+1's loads done; kt+2/kt+3 in flight
    __builtin_amdgcn_s_barrier();
  }

  // epilogue: C[row = tm*256 + wm*128 + i*16 + lh*4 + rr][col = tn*256 + wn*64 + j*16 + lr]
  const int gcolbase = tn * 256 + wn * 64 + lr;
  float bv[4];
#pragma unroll
  for (int j = 0; j < 4; ++j) bv[j] = bias[e * Nd + gcolbase + j * 16];
#pragma unroll
  for (int i = 0; i < 8; ++i) {
#pragma unroll
    for (int rr = 0; rr < 4; ++rr) {
      int grow = tm * 256 + wm * 128 + i * 16 + lh * 4 + rr;
      if (grow < M) {
        if (MODE == 1) {
          size_t rowoff = (size_t)(ms + grow) * H_;
#pragma unroll
          for (int j = 0; j < 4; ++j) {
            float v = acc[i][j][rr] + bv[j];
            v = fmaxf(v, 0.f);
            hbo[rowoff + gcolbase + j * 16] = f2bf(v);
          }
        } else {
          int tok = perm[ms + grow];
          size_t rowoff = (size_t)tok * D_;
#pragma unroll
          for (int j = 0; j < 4; ++j)
            out[rowoff + gcolbase + j * 16] = acc[i][j][rr] + bv[j];
        }
      }
    }
  }
#undef STAGE
#undef AOFF
}

extern "C" void kernel_launch(void* const* d_in, const int* in_sizes, int n_in,
                              void* d_out, int out_size, void* d_ws, size_t ws_size,
                              hipStream_t stream) {
  const float* x  = (const float*)d_in[0];
  const float* W1 = (const float*)d_in[1];
  const float* b1 = (const float*)d_in[2];
  const float* W2 = (const float*)d_in[3];
  const float* b2 = (const float*)d_in[4];
  const float* Wr = (const float*)d_in[5];
  const float* br = (const float*)d_in[6];
  float* out = (float*)d_out;

  // workspace layout (needs ~302.3 MB)
  char* ws = (char*)d_ws;
  ushort_t* W1t   = (ushort_t*)(ws);                    // [E][H][D] bf16: 67108864 B
  ushort_t* W2t   = (ushort_t*)(ws + 67108864);         // [E][D][H] bf16: 67108864 B
  ushort_t* xg    = (ushort_t*)(ws + 134217728);        // [N][D]   bf16: 33554432 B
  ushort_t* hb    = (ushort_t*)(ws + 167772160);        // [N][H]   bf16: 134217728 B
  float*    rawbase = (float*)(ws + 301989888);         // [E][D] f32
  float*    adj   = (float*)(ws + 302022656);           // [E][D] f32
  int*      idx   = (int*)(ws + 302055424);             // [N]
  int*      perm  = (int*)(ws + 302120960);             // [N]
  int*      counts = (int*)(ws + 302186496);            // 8 + 8 cursor
  int*      cursor = counts + 8;
  int*      offsets = (int*)(ws + 302186624);           // 9 ints
  int*      meta   = (int*)(ws + 302186752);            // [n1, n2]
  int*      work1  = (int*)(ws + 302186880);            // <=2048 ints
  int*      work2  = (int*)(ws + 302195072);            // <=2048 ints

  init_kernel<<<32, 256, 0, stream>>>(counts, rawbase);
  transpose_bf16<0><<<dim3(H_ / 64, D_ / 64, E_), 256, 0, stream>>>(W1, W1t, D_, H_,
                                                                    nullptr, nullptr);
  transpose_bf16<1><<<dim3(D_ / 64, H_ / 64, E_), 256, 0, stream>>>(W2, W2t, H_, D_,
                                                                    b1, rawbase);
  adj_kernel<<<32, 256, 0, stream>>>(rawbase, b2, adj);
  router_kernel<<<512, 256, 0, stream>>>(x, Wr, br, idx, counts);
  scan_build<<<1, 64, 0, stream>>>(counts, offsets, work1, work2, meta);
  scatter_kernel<<<NTOK / 4, 256, 0, stream>>>(x, idx, offsets, cursor, perm, xg);
  // worst-case tile counts: sum_e ceil(cnt_e/256) <= 71  ->  71*16=1136, 71*4=284
  ffn_gemm<1><<<1136, 512, 0, stream>>>(xg, W1t, b1, offsets, nullptr, nullptr, hb,
                                        work1, meta + 0);
  ffn_gemm<2><<<284, 512, 0, stream>>>(hb, W2t, adj, offsets, perm, out, nullptr,
                                       work2, meta + 1);
}